// Round 10
// baseline (496.084 us; speedup 1.0000x reference)
//
#include <hip/hip_runtime.h>

// LSTMClassifier round 9: pair-split epilogue with duplicated MFMA.
//   grid = 128 blocks x 1024 threads (16 waves). Block = 16 batch rows.
//   Waves 0-7:  L0, (u = (wv>>1)&3, q = wv&1): compute tile-u's MFMAs
//               (duplicated across the q-pair), epilogue cells {2q, 2q+1}.
//               h0(k) = f(h0(k-1))                  [k <= 511]
//   Waves 8-15: L1 likewise: h1(k-1) = f(h0(k-1), h1(k-2))   [k >= 1]
//   Per-wave trans issue halves (2 cells = 14 trans); 4 waves/SIMD.
//   One s_barrier per iter. XOR-rotated h layout; merged-rcp activations
//   (5 exp2 + 2 rcp per cell); -log2e pre-scaled into weights/biases.

typedef _Float16 half8    __attribute__((ext_vector_type(8)));
typedef float    float4_t __attribute__((ext_vector_type(4)));
typedef float    float2_t __attribute__((ext_vector_type(2)));

#define T_STEPS 512
#define SIG_K  (-1.442695040888963f)    // -log2(e)
#define TANH_K (-2.885390081777927f)    // -2*log2(e)

__device__ __forceinline__ int hoff(int slot, int row, int kb, int lo) {
    return slot * 1024 + row * 64 + (((kb + row) & 7) << 3) + lo;
}

// inputs pre-scaled: zi,zf,zo by -log2e; zg by -2log2e. c updated in place.
// returns h = sigmoid(o)*tanh(c'). 5 exp2 + 2 rcp.
__device__ __forceinline__ float lstm_cell(float zi, float zf, float zg, float zo,
                                           float& c) {
    const float ei = __builtin_amdgcn_exp2f(zi);
    const float ef = __builtin_amdgcn_exp2f(zf);
    const float v  = __builtin_amdgcn_exp2f(zg);
    const float eo = __builtin_amdgcn_exp2f(zo);
    const float pi = 1.f + ei, pf = 1.f + ef, pv = 1.f + v, po = 1.f + eo;
    const float A   = pi * pv;
    const float num = fmaf(c, A, (1.f - v) * pf);
    const float cn  = num * __builtin_amdgcn_rcpf(pf * A);
    c = cn;
    const float u = __builtin_amdgcn_exp2f(cn * TANH_K);
    return (1.f - u) * __builtin_amdgcn_rcpf(po * (1.f + u));
}

extern "C" __global__ __launch_bounds__(1024, 1)
void lstm2_mfma(const float* __restrict__ x,
                const float* __restrict__ w_ih0, const float* __restrict__ w_hh0,
                const float* __restrict__ b_ih0, const float* __restrict__ b_hh0,
                const float* __restrict__ w_ih1, const float* __restrict__ w_hh1,
                const float* __restrict__ b_ih1, const float* __restrict__ b_hh1,
                const float* __restrict__ w_fc,  const float* __restrict__ b_fc,
                float* __restrict__ out)
{
    __shared__ float    x_lds[T_STEPS][16];    // 32 KB
    __shared__ _Float16 bufA[2 * 1024];        // h0, 2 slots, 4 KB
    __shared__ _Float16 bufB[2 * 1024];        // h1, 2 slots, 4 KB
    __shared__ float    hfin[16][68];

    const int tid  = threadIdx.x;
    const int wv   = tid >> 6;          // wave 0..15
    const int lane = tid & 63;
    const int cr   = lane & 15;         // A-row (batch) / C-col (unit)
    const int kg   = lane >> 4;         // k-group 0..3
    const int rb   = kg * 4;            // C-frag row base
    const int b0   = blockIdx.x * 16;
    const bool isL0 = (wv < 8);
    const int u    = (wv >> 1) & 3;     // unit tile 0..3
    const int q    = __builtin_amdgcn_readfirstlane(wv & 1);  // row-pair half
    const int ucol = u * 16 + cr;       // this lane's unit 0..63
    const int wkb  = 2 * u + (cr >> 3); // write-side 8-half block index

    // ---- stage x[b0..b0+15][t] -> x_lds[t][r]; zero h bufs ----
    for (int idx = tid; idx < 16 * T_STEPS; idx += 1024) {
        const int r = idx >> 9, t = idx & (T_STEPS - 1);
        x_lds[t][r] = x[(long)(b0 + r) * T_STEPS + t];
    }
    for (int idx = tid; idx < 2 * 1024; idx += 1024) {
        bufA[idx] = (_Float16)0.f;
        bufB[idx] = (_Float16)0.f;
    }

    // ---- per-lane weight fragments (registers), role-specialized ----
    half8 wf[4][4];                 // L0 uses [g][0..1]; L1 uses [g][0..3]
    float bias[4], wi0[4];
    #pragma unroll
    for (int g = 0; g < 4; ++g) {
        const float sc = (g == 2) ? TANH_K : SIG_K;   // gate 2 = g (tanh)
        const int col = g * 64 + ucol;                // PyTorch i,f,g,o
        if (isL0) {
            bias[g] = (b_ih0[col] + b_hh0[col]) * sc;
            wi0[g]  = w_ih0[col] * sc;
            #pragma unroll
            for (int kt = 0; kt < 2; ++kt) {
                const float* src = w_hh0 + col * 64 + kt * 32 + kg * 8;
                #pragma unroll
                for (int i = 0; i < 8; ++i) wf[g][kt][i] = (_Float16)(src[i] * sc);
            }
        } else {
            bias[g] = (b_ih1[col] + b_hh1[col]) * sc;
            #pragma unroll
            for (int kt = 0; kt < 4; ++kt) {
                const int k0 = kt * 32 + kg * 8;   // 0..119 in [h0;h1]
                const float* src = (k0 < 64) ? (w_ih1 + col * 64 + k0)
                                             : (w_hh1 + col * 64 + (k0 - 64));
                #pragma unroll
                for (int i = 0; i < 8; ++i) wf[g][kt][i] = (_Float16)(src[i] * sc);
            }
        }
    }

    const float4_t zero4 = {0.f, 0.f, 0.f, 0.f};
    float cc[2] = {0.f, 0.f};           // c-state for this wave's 2 cells
    float hv[2] = {0.f, 0.f};

    __syncthreads();   // x_lds + zeroed bufs visible

    for (int k = 0; k <= T_STEPS; ++k) {
        const int sA = (k + 1) & 1;     // slot of h0(k-1)  (h0(-1)=0 in slot 1)

        if (isL0) {
            if (k < T_STEPS) {          // ---- L0: h0(k), cells {2q, 2q+1} ----
                const half8 a0 = *(const half8*)&bufA[hoff(sA, cr, kg,     0)];
                const half8 a1 = *(const half8*)&bufA[hoff(sA, cr, 4 + kg, 0)];
                float4_t acc[4];
                #pragma unroll
                for (int g = 0; g < 4; ++g) {
                    acc[g] = __builtin_amdgcn_mfma_f32_16x16x32_f16(a0, wf[g][0], zero4, 0, 0, 0);
                    acc[g] = __builtin_amdgcn_mfma_f32_16x16x32_f16(a1, wf[g][1], acc[g], 0, 0, 0);
                }
                float z[4][2];
                if (q == 0) {
                    #pragma unroll
                    for (int g = 0; g < 4; ++g) { z[g][0] = acc[g][0]; z[g][1] = acc[g][1]; }
                } else {
                    #pragma unroll
                    for (int g = 0; g < 4; ++g) { z[g][0] = acc[g][2]; z[g][1] = acc[g][3]; }
                }
                const float2_t xq = *(const float2_t*)&x_lds[k][rb + 2 * q];
                #pragma unroll
                for (int ii = 0; ii < 2; ++ii) {
                    const float xv = xq[ii];
                    const float zi = fmaf(xv, wi0[0], z[0][ii] + bias[0]);
                    const float zf = fmaf(xv, wi0[1], z[1][ii] + bias[1]);
                    const float zg = fmaf(xv, wi0[2], z[2][ii] + bias[2]);
                    const float zo = fmaf(xv, wi0[3], z[3][ii] + bias[3]);
                    const float h = lstm_cell(zi, zf, zg, zo, cc[ii]);
                    bufA[hoff(k & 1, rb + 2 * q + ii, wkb, cr & 7)] = (_Float16)h;
                }
            }
        } else {
            if (k >= 1) {               // ---- L1: h1(k-1), cells {2q, 2q+1} ----
                const int sB = k & 1;   // slot of h1(k-2)  (h1(-1)=0 in slot 1)
                const half8 a0  = *(const half8*)&bufA[hoff(sA, cr, kg,     0)];
                const half8 a1  = *(const half8*)&bufA[hoff(sA, cr, 4 + kg, 0)];
                const half8 bh0 = *(const half8*)&bufB[hoff(sB, cr, kg,     0)];
                const half8 bh1 = *(const half8*)&bufB[hoff(sB, cr, 4 + kg, 0)];
                float4_t acc[4];
                #pragma unroll
                for (int g = 0; g < 4; ++g) {
                    acc[g] = __builtin_amdgcn_mfma_f32_16x16x32_f16(a0,  wf[g][0], zero4, 0, 0, 0);
                    acc[g] = __builtin_amdgcn_mfma_f32_16x16x32_f16(a1,  wf[g][1], acc[g], 0, 0, 0);
                    acc[g] = __builtin_amdgcn_mfma_f32_16x16x32_f16(bh0, wf[g][2], acc[g], 0, 0, 0);
                    acc[g] = __builtin_amdgcn_mfma_f32_16x16x32_f16(bh1, wf[g][3], acc[g], 0, 0, 0);
                }
                float z[4][2];
                if (q == 0) {
                    #pragma unroll
                    for (int g = 0; g < 4; ++g) { z[g][0] = acc[g][0]; z[g][1] = acc[g][1]; }
                } else {
                    #pragma unroll
                    for (int g = 0; g < 4; ++g) { z[g][0] = acc[g][2]; z[g][1] = acc[g][3]; }
                }
                #pragma unroll
                for (int ii = 0; ii < 2; ++ii) {
                    const float zi = z[0][ii] + bias[0];
                    const float zf = z[1][ii] + bias[1];
                    const float zg = z[2][ii] + bias[2];
                    const float zo = z[3][ii] + bias[3];
                    hv[ii] = lstm_cell(zi, zf, zg, zo, cc[ii]);
                    bufB[hoff((k + 1) & 1, rb + 2 * q + ii, wkb, cr & 7)] = (_Float16)hv[ii];
                }
            }
        }

        __syncthreads();    // writes of iter k visible at iter k+1
    }

    // ---- FC head: h_last = h1(511), held by L1 waves (2 rows each) ----
    if (!isL0) {
        hfin[rb + 2 * q + 0][ucol] = hv[0];
        hfin[rb + 2 * q + 1][ucol] = hv[1];
    }
    __syncthreads();

    if (tid < 48) {
        const int row = tid / 3, cls = tid - row * 3;
        float s = b_fc[cls];
        const float* wr = w_fc + cls * 64;
        #pragma unroll 8
        for (int uu = 0; uu < 64; ++uu) s += hfin[row][uu] * wr[uu];
        out[(long)(b0 + row) * 3 + cls] = s;
    }
}

extern "C" void kernel_launch(void* const* d_in, const int* in_sizes, int n_in,
                              void* d_out, int out_size, void* d_ws, size_t ws_size,
                              hipStream_t stream) {
    const float* xx     = (const float*)d_in[0];
    const float* w_ih0  = (const float*)d_in[1];
    const float* w_hh0  = (const float*)d_in[2];
    const float* b_ih0  = (const float*)d_in[3];
    const float* b_hh0  = (const float*)d_in[4];
    const float* w_ih1  = (const float*)d_in[5];
    const float* w_hh1  = (const float*)d_in[6];
    const float* b_ih1  = (const float*)d_in[7];
    const float* b_hh1  = (const float*)d_in[8];
    const float* w_fc   = (const float*)d_in[9];
    const float* b_fc   = (const float*)d_in[10];
    float* out = (float*)d_out;

    lstm2_mfma<<<dim3(128), dim3(1024), 0, stream>>>(
        xx, w_ih0, w_hh0, b_ih0, b_hh0,
        w_ih1, w_hh1, b_ih1, b_hh1, w_fc, b_fc, out);
}

// Round 11
// 268.722 us; speedup vs baseline: 1.8461x; 1.8461x over previous
//
#include <hip/hip_runtime.h>

// LSTMClassifier round 10: all-256-CU version of round 8.
//   grid = 256 blocks x 512 threads (8 waves). Block = 8 batch rows.
//   Batch row b -> M-row 4*(b>>1)+(b&1): every kg-group's first 2 C-frag
//   rows (acc[g][0..1]) are real cells; junk M-rows stay exactly 0 (zeroed,
//   never written) -> 2 real cells/lane, no shuffles, no junk epilogue.
//   Waves 0-3: L0 tile u: h0(k) = f(h0(k-1))               [k <= 511]
//   Waves 4-7: L1 tile u: h1(k-1) = f(h0(k-1), h1(k-2))    [k >= 1]
//   One s_barrier per iter. XOR-rotated h layout; merged-rcp activations
//   (5 exp2 + 2 rcp per cell); -log2e pre-scaled into weights/biases.

typedef _Float16 half8    __attribute__((ext_vector_type(8)));
typedef float    float4_t __attribute__((ext_vector_type(4)));
typedef float    float2_t __attribute__((ext_vector_type(2)));

#define T_STEPS 512
#define SIG_K  (-1.442695040888963f)    // -log2(e)
#define TANH_K (-2.885390081777927f)    // -2*log2(e)

__device__ __forceinline__ int hoff(int slot, int row, int kb, int lo) {
    return slot * 1024 + row * 64 + (((kb + row) & 7) << 3) + lo;
}

// inputs pre-scaled: zi,zf,zo by -log2e; zg by -2log2e. c updated in place.
// returns h = sigmoid(o)*tanh(c'). 5 exp2 + 2 rcp.
__device__ __forceinline__ float lstm_cell(float zi, float zf, float zg, float zo,
                                           float& c) {
    const float ei = __builtin_amdgcn_exp2f(zi);
    const float ef = __builtin_amdgcn_exp2f(zf);
    const float v  = __builtin_amdgcn_exp2f(zg);
    const float eo = __builtin_amdgcn_exp2f(zo);
    const float pi = 1.f + ei, pf = 1.f + ef, pv = 1.f + v, po = 1.f + eo;
    const float A   = pi * pv;
    const float num = fmaf(c, A, (1.f - v) * pf);
    const float cn  = num * __builtin_amdgcn_rcpf(pf * A);
    c = cn;
    const float u = __builtin_amdgcn_exp2f(cn * TANH_K);
    return (1.f - u) * __builtin_amdgcn_rcpf(po * (1.f + u));
}

extern "C" __global__ __launch_bounds__(512, 1)
void lstm2_mfma(const float* __restrict__ x,
                const float* __restrict__ w_ih0, const float* __restrict__ w_hh0,
                const float* __restrict__ b_ih0, const float* __restrict__ b_hh0,
                const float* __restrict__ w_ih1, const float* __restrict__ w_hh1,
                const float* __restrict__ b_ih1, const float* __restrict__ b_hh1,
                const float* __restrict__ w_fc,  const float* __restrict__ b_fc,
                float* __restrict__ out)
{
    __shared__ float    x_lds[T_STEPS][8];     // 16 KB (compact batch rows)
    __shared__ _Float16 bufA[2 * 1024];        // h0, 2 slots, 4 KB
    __shared__ _Float16 bufB[2 * 1024];        // h1, 2 slots, 4 KB
    __shared__ float    hfin[8][68];

    const int tid  = threadIdx.x;
    const int wv   = tid >> 6;          // wave 0..7
    const int lane = tid & 63;
    const int cr   = lane & 15;         // A-row (M-row) / C-col (unit)
    const int kg   = lane >> 4;         // k-group 0..3
    const int rb   = kg * 4;            // C-frag row base
    const int b0   = blockIdx.x * 8;    // this block's 8 batch rows
    const bool isL0 = (wv < 4);
    const int u    = wv & 3;            // unit tile 0..3
    const int ucol = u * 16 + cr;       // this lane's unit 0..63
    const int wkb  = 2 * u + (cr >> 3); // write-side 8-half block index

    // ---- stage x[b0..b0+7][t] -> x_lds[t][r] (compact); zero h bufs ----
    for (int idx = tid; idx < 8 * T_STEPS; idx += 512) {
        const int r = idx >> 9, t = idx & (T_STEPS - 1);
        x_lds[t][r] = x[(long)(b0 + r) * T_STEPS + t];
    }
    for (int idx = tid; idx < 2 * 1024; idx += 512) {
        bufA[idx] = (_Float16)0.f;      // junk M-rows stay 0 forever
        bufB[idx] = (_Float16)0.f;
    }

    // ---- per-lane weight fragments (registers), role-specialized ----
    half8 wf[4][4];                 // L0 uses [g][0..1]; L1 uses [g][0..3]
    float bias[4], wi0[4];
    #pragma unroll
    for (int g = 0; g < 4; ++g) {
        const float sc = (g == 2) ? TANH_K : SIG_K;   // gate 2 = g (tanh)
        const int col = g * 64 + ucol;                // PyTorch i,f,g,o
        if (isL0) {
            bias[g] = (b_ih0[col] + b_hh0[col]) * sc;
            wi0[g]  = w_ih0[col] * sc;
            #pragma unroll
            for (int kt = 0; kt < 2; ++kt) {
                const float* src = w_hh0 + col * 64 + kt * 32 + kg * 8;
                #pragma unroll
                for (int i = 0; i < 8; ++i) wf[g][kt][i] = (_Float16)(src[i] * sc);
            }
        } else {
            bias[g] = (b_ih1[col] + b_hh1[col]) * sc;
            #pragma unroll
            for (int kt = 0; kt < 4; ++kt) {
                const int k0 = kt * 32 + kg * 8;   // 0..119 in [h0;h1]
                const float* src = (k0 < 64) ? (w_ih1 + col * 64 + k0)
                                             : (w_hh1 + col * 64 + (k0 - 64));
                #pragma unroll
                for (int i = 0; i < 8; ++i) wf[g][kt][i] = (_Float16)(src[i] * sc);
            }
        }
    }

    const float4_t zero4 = {0.f, 0.f, 0.f, 0.f};
    float cc[2] = {0.f, 0.f};           // c-state: this lane's 2 real cells
    float hv[2] = {0.f, 0.f};           // (batch rows 2*kg, 2*kg+1)

    __syncthreads();   // x_lds + zeroed bufs visible

    for (int k = 0; k <= T_STEPS; ++k) {
        const int sA = (k + 1) & 1;     // slot of h0(k-1)  (h0(-1)=0 in slot 1)

        if (isL0) {
            if (k < T_STEPS) {          // ---- L0: h0(k), cells rows rb, rb+1 ----
                const half8 a0 = *(const half8*)&bufA[hoff(sA, cr, kg,     0)];
                const half8 a1 = *(const half8*)&bufA[hoff(sA, cr, 4 + kg, 0)];
                float4_t acc[4];
                #pragma unroll
                for (int g = 0; g < 4; ++g) {
                    acc[g] = __builtin_amdgcn_mfma_f32_16x16x32_f16(a0, wf[g][0], zero4, 0, 0, 0);
                    acc[g] = __builtin_amdgcn_mfma_f32_16x16x32_f16(a1, wf[g][1], acc[g], 0, 0, 0);
                }
                const float2_t xq = *(const float2_t*)&x_lds[k][2 * kg];
                #pragma unroll
                for (int ii = 0; ii < 2; ++ii) {
                    const float xv = xq[ii];
                    const float zi = fmaf(xv, wi0[0], acc[0][ii] + bias[0]);
                    const float zf = fmaf(xv, wi0[1], acc[1][ii] + bias[1]);
                    const float zg = fmaf(xv, wi0[2], acc[2][ii] + bias[2]);
                    const float zo = fmaf(xv, wi0[3], acc[3][ii] + bias[3]);
                    const float h = lstm_cell(zi, zf, zg, zo, cc[ii]);
                    bufA[hoff(k & 1, rb + ii, wkb, cr & 7)] = (_Float16)h;
                }
            }
        } else {
            if (k >= 1) {               // ---- L1: h1(k-1), cells rows rb, rb+1 ----
                const int sB = k & 1;   // slot of h1(k-2)  (h1(-1)=0 in slot 1)
                const half8 a0  = *(const half8*)&bufA[hoff(sA, cr, kg,     0)];
                const half8 a1  = *(const half8*)&bufA[hoff(sA, cr, 4 + kg, 0)];
                const half8 bh0 = *(const half8*)&bufB[hoff(sB, cr, kg,     0)];
                const half8 bh1 = *(const half8*)&bufB[hoff(sB, cr, 4 + kg, 0)];
                float4_t acc[4];
                #pragma unroll
                for (int g = 0; g < 4; ++g) {
                    acc[g] = __builtin_amdgcn_mfma_f32_16x16x32_f16(a0,  wf[g][0], zero4, 0, 0, 0);
                    acc[g] = __builtin_amdgcn_mfma_f32_16x16x32_f16(a1,  wf[g][1], acc[g], 0, 0, 0);
                    acc[g] = __builtin_amdgcn_mfma_f32_16x16x32_f16(bh0, wf[g][2], acc[g], 0, 0, 0);
                    acc[g] = __builtin_amdgcn_mfma_f32_16x16x32_f16(bh1, wf[g][3], acc[g], 0, 0, 0);
                }
                #pragma unroll
                for (int ii = 0; ii < 2; ++ii) {
                    const float zi = acc[0][ii] + bias[0];
                    const float zf = acc[1][ii] + bias[1];
                    const float zg = acc[2][ii] + bias[2];
                    const float zo = acc[3][ii] + bias[3];
                    hv[ii] = lstm_cell(zi, zf, zg, zo, cc[ii]);
                    bufB[hoff((k + 1) & 1, rb + ii, wkb, cr & 7)] = (_Float16)hv[ii];
                }
            }
        }

        __syncthreads();    // writes of iter k visible at iter k+1
    }

    // ---- FC head: h_last = h1(511), held by L1 waves (2 batch rows each) ----
    if (!isL0) {
        hfin[2 * kg + 0][ucol] = hv[0];
        hfin[2 * kg + 1][ucol] = hv[1];
    }
    __syncthreads();

    if (tid < 24) {
        const int row = tid / 3, cls = tid - row * 3;
        float s = b_fc[cls];
        const float* wr = w_fc + cls * 64;
        #pragma unroll 8
        for (int uu = 0; uu < 64; ++uu) s += hfin[row][uu] * wr[uu];
        out[(long)(b0 + row) * 3 + cls] = s;
    }
}

extern "C" void kernel_launch(void* const* d_in, const int* in_sizes, int n_in,
                              void* d_out, int out_size, void* d_ws, size_t ws_size,
                              hipStream_t stream) {
    const float* xx     = (const float*)d_in[0];
    const float* w_ih0  = (const float*)d_in[1];
    const float* w_hh0  = (const float*)d_in[2];
    const float* b_ih0  = (const float*)d_in[3];
    const float* b_hh0  = (const float*)d_in[4];
    const float* w_ih1  = (const float*)d_in[5];
    const float* w_hh1  = (const float*)d_in[6];
    const float* b_ih1  = (const float*)d_in[7];
    const float* b_hh1  = (const float*)d_in[8];
    const float* w_fc   = (const float*)d_in[9];
    const float* b_fc   = (const float*)d_in[10];
    float* out = (float*)d_out;

    lstm2_mfma<<<dim3(256), dim3(512), 0, stream>>>(
        xx, w_ih0, w_hh0, b_ih0, b_hh0,
        w_ih1, w_hh1, b_ih1, b_hh1, w_fc, b_fc, out);
}